// Round 6
// baseline (1595.235 us; speedup 1.0000x reference)
//
#include <hip/hip_runtime.h>
#include <stdint.h>

typedef unsigned short u16;
typedef __attribute__((ext_vector_type(8))) short short8;
typedef __attribute__((ext_vector_type(4))) float f32x4;

#define NE   8
#define DIN  2048
#define DOUT 8192
#define NTOK 16384

__device__ __forceinline__ u16 f2bf(float f) {
  uint32_t u = __builtin_bit_cast(uint32_t, f);
  u += 0x7FFFu + ((u >> 16) & 1u);   // RNE (inputs are finite normals)
  return (u16)(u >> 16);
}

__global__ __launch_bounds__(256) void cvt_f32_bf16(const float* __restrict__ src,
                                                    u16* __restrict__ dst, size_t n) {
  size_t i = ((size_t)blockIdx.x * 256 + threadIdx.x) * 8;
  const size_t stride = (size_t)gridDim.x * 256 * 8;
  for (; i < n; i += stride) {
    f32x4 a = *(const f32x4*)(src + i);
    f32x4 b = *(const f32x4*)(src + i + 4);
    short8 o;
    o[0] = (short)f2bf(a[0]); o[1] = (short)f2bf(a[1]);
    o[2] = (short)f2bf(a[2]); o[3] = (short)f2bf(a[3]);
    o[4] = (short)f2bf(b[0]); o[5] = (short)f2bf(b[1]);
    o[6] = (short)f2bf(b[2]); o[7] = (short)f2bf(b[3]);
    *(short8*)(dst + i) = o;
  }
}

#define GLOAD_LDS16(g, l) __builtin_amdgcn_global_load_lds( \
    (const __attribute__((address_space(1))) void*)(g),     \
    (__attribute__((address_space(3))) void*)(l), 16, 0, 0)

// ---------------------------------------------------------------------------
// r6: r3's proven geometry (256x256, BK=64, 16x16x32 MFMA, 8 waves 2x4,
// granule swizzle with measured-0 conflicts, 8 barriers/K-tile, counted
// vmcnt) + ONE mechanism change: fragment ds_reads are software-pipelined
// one phase ahead into a second register set, so each MM segment's MFMA
// consumes registers loaded a full phase earlier (no lgkm head-stall) and
// LDS servicing hides under MFMA + barrier waits (T3/T4 applied to ds_read).
// Segments per K-tile (phase = (kh, m-half); reads balanced 4/8/4/8):
//   S1: rd Ao<-[m4-7]kh0      ; MM(Ae,Be -> m0-3)        | bar
//   S2: stage A0(t+1); VMW(2|0: last tile)               | bar
//   S3: rd Ae<-[m0-3]kh1, Bo<-kh1 ; MM(Ao,Be -> m4-7)    | bar
//   S4: stage B0(t+1)                                    | bar
//   S5: rd Ao<-[m4-7]kh1      ; MM(Ae,Bo -> m0-3)        | bar
//   S6: stage A1(t+1); VMW(2)                            | bar
//   S7: rd Ae,Be <- kh0(NEXT) ; MM(Ao,Bo -> m4-7)        | bar
//   S8: stage B1(t+1)                                    | bar
// Reads of freshly-staged LDS always sit AFTER the {own-vmw -> barrier}
// publish point (cross-wave vmcnt rule). VMW(2)@S2 drains cur-kh1 (issued
// t-1 S6/S8); VMW(2)@S6 drains nxt-kh0 (S2/S4); last tile VMW(0)@S2.
// ---------------------------------------------------------------------------
__global__ __launch_bounds__(512, 2) void moe_gemm8(
    const u16* __restrict__ Xb, const u16* __restrict__ Wb,
    const int* __restrict__ counts, const float* __restrict__ bias,
    float* __restrict__ C) {
  extern __shared__ u16 sm[];  // 65536 u16

  const int tid = threadIdx.x;
  const int l = tid & 63;
  const int wid = tid >> 6;      // 0..7
  const int wr = wid >> 2;       // 0..1  (M halves of 128)
  const int wc = wid & 3;        // 0..3  (N quarters of 64)

  // XCD-bijective swizzle: 2048 blocks, 256/XCD == tiles/expert => expert==XCD
  const int id = blockIdx.x;
  const int swz = (id & 7) * 256 + (id >> 3);
  const int e = swz >> 8;
  const int rem = swz & 255;
  const int tn = rem >> 3;       // 0..31 (8 consecutive blocks share B-panel)
  const int tm = rem & 7;        // 0..7

  int off = 0;
  for (int i = 0; i < e; ++i) off += counts[i];
  const int row0 = off + tm * 256;
  const int col0 = tn * 256;
  const size_t wbase = (size_t)e * DOUT * DIN + (size_t)col0 * DIN;

  // -- staging per-lane constants (pre-swizzled global source, linear dest)
  const int rl = l >> 2;                     // row within 16-row slice
  const int q = (l & 3) ^ ((l >> 3) & 3);    // source k-granule (inverse swz)
  const int s0 = wid * 2, s1 = s0 + 1;       // this wave's 2 slices of 16
  const u16* pA0 = Xb + (size_t)(row0 + s0 * 16 + rl) * DIN + q * 8;
  const u16* pA1 = Xb + (size_t)(row0 + s1 * 16 + rl) * DIN + q * 8;
  const u16* pB0 = Wb + wbase + (size_t)(s0 * 16 + rl) * DIN + q * 8;
  const u16* pB1 = Wb + wbase + (size_t)(s1 * 16 + rl) * DIN + q * 8;

  // -- fragment-read per-lane constants (16x16 layout, r3-verified swizzle)
  const int f0 = ((l & 15) >> 1) & 3;
  const int gph = (l >> 4) ^ f0;             // physical granule 0..3
  const int aoff = (wr * 128 + (l & 15)) * 32 + gph * 8;
  const int boff = (wc * 64 + (l & 15)) * 32 + gph * 8;

  f32x4 acc[8][4] = {};
  short8 Ae[4], Ao[4], Be[4], Bo[4];

#define SMA(buf, kh) (sm + (buf) * 32768 + (kh) * 8192)
#define SMB(buf, kh) (sm + (buf) * 32768 + 16384 + (kh) * 8192)
#define STAGE_A(buf, kt, kh) do { const int ko = (kt) * 64 + (kh) * 32; \
    GLOAD_LDS16(pA0 + ko, SMA(buf, kh) + s0 * 512);                     \
    GLOAD_LDS16(pA1 + ko, SMA(buf, kh) + s1 * 512); } while (0)
#define STAGE_B(buf, kt, kh) do { const int ko = (kt) * 64 + (kh) * 32; \
    GLOAD_LDS16(pB0 + ko, SMB(buf, kh) + s0 * 512);                     \
    GLOAD_LDS16(pB1 + ko, SMB(buf, kh) + s1 * 512); } while (0)
#define RA(arr, buf, kh, mb) do { _Pragma("unroll") for (int mf = 0; mf < 4; ++mf) \
    arr[mf] = *(const short8*)(SMA(buf, kh) + aoff + ((mb) + mf) * 512); } while (0)
#define RB(arr, buf, kh) do { _Pragma("unroll") for (int nf = 0; nf < 4; ++nf) \
    arr[nf] = *(const short8*)(SMB(buf, kh) + boff + nf * 512); } while (0)
#define FENCE() asm volatile("" ::: "memory")
#define BAR() do { FENCE(); __builtin_amdgcn_s_barrier(); FENCE(); } while (0)
#define VMW(N) asm volatile("s_waitcnt vmcnt(" #N ")" ::: "memory")
#define MMQ(A, B, mb) do { __builtin_amdgcn_s_setprio(1);                          \
    _Pragma("unroll") for (int mf = 0; mf < 4; ++mf)                               \
      _Pragma("unroll") for (int nf = 0; nf < 4; ++nf)                             \
        acc[(mb) + mf][nf] =                                                       \
          __builtin_amdgcn_mfma_f32_16x16x32_bf16(A[mf], B[nf], acc[(mb) + mf][nf], 0, 0, 0); \
    __builtin_amdgcn_s_setprio(0); } while (0)

  const int NKT = DIN / 64;  // 32 K-tiles

  // prologue: tile 0 staged (kh0 first); kh0 published; preload S1 regs.
  STAGE_A(0, 0, 0); STAGE_B(0, 0, 0); STAGE_A(0, 0, 1); STAGE_B(0, 0, 1);
  VMW(4);
  BAR();
  RA(Ae, 0, 0, 0); RB(Be, 0, 0);

  for (int kt = 0; kt < NKT; kt += 2) {
#define TILE(cur, nxt, t) do {                                          \
    const bool hn = (t) + 1 < NKT;                                      \
    /* S1 */                                                            \
    RA(Ao, cur, 0, 4);                                                  \
    MMQ(Ae, Be, 0);                                                     \
    BAR();                                                              \
    /* S2 */                                                            \
    if (hn) { STAGE_A(nxt, (t) + 1, 0); VMW(2); } else VMW(0);          \
    BAR();                                                              \
    /* S3 */                                                            \
    RA(Ae, cur, 1, 0); RB(Bo, cur, 1);                                  \
    MMQ(Ao, Be, 4);                                                     \
    BAR();                                                              \
    /* S4 */                                                            \
    if (hn) STAGE_B(nxt, (t) + 1, 0);                                   \
    BAR();                                                              \
    /* S5 */                                                            \
    RA(Ao, cur, 1, 4);                                                  \
    MMQ(Ae, Bo, 0);                                                     \
    BAR();                                                              \
    /* S6 */                                                            \
    if (hn) { STAGE_A(nxt, (t) + 1, 1); VMW(2); }                       \
    BAR();                                                              \
    /* S7 */                                                            \
    if (hn) { RA(Ae, nxt, 0, 0); RB(Be, nxt, 0); }                      \
    MMQ(Ao, Bo, 4);                                                     \
    BAR();                                                              \
    /* S8 */                                                            \
    if (hn) STAGE_B(nxt, (t) + 1, 1);                                   \
    BAR(); } while (0)
    TILE(0, 1, kt);
    TILE(1, 0, kt + 1);
#undef TILE
  }

  // epilogue: C/D layout col=lane&15, row=(lane>>4)*4+j  [m89]
  const int rb = row0 + wr * 128 + ((l >> 4) << 2);
  const int cb = col0 + wc * 64 + (l & 15);
#pragma unroll
  for (int n = 0; n < 4; ++n) {
    const int col = cb + n * 16;
    const float bv = bias[e * DOUT + col];
#pragma unroll
    for (int m = 0; m < 8; ++m) {
      const int r = rb + m * 16;
#pragma unroll
      for (int j = 0; j < 4; ++j)
        C[(size_t)(r + j) * DOUT + col] = acc[m][n][j] + bv;
    }
  }
}

// ---------------------------------------------------------------------------
// Fallback (ws too small): fused fp32->bf16 staging, 128x128 m97 structure.
// ---------------------------------------------------------------------------
__global__ __launch_bounds__(256) void moe_gemm_fused(
    const float* __restrict__ Xf, const float* __restrict__ Wf,
    const int* __restrict__ counts, const float* __restrict__ bias,
    float* __restrict__ C) {
  __shared__ __align__(16) u16 lds[2][2][128 * 32];

  const int tid = threadIdx.x;
  const int lane = tid & 63;
  const int wid = tid >> 6;
  const int wr = wid >> 1;
  const int wc = wid & 1;

  const int id = blockIdx.x;
  const int swz = (id & 7) * ((int)gridDim.x >> 3) + (id >> 3);
  const int e = swz >> 10;
  const int rem = swz & 1023;
  const int tn = rem >> 4;
  const int tml = rem & 15;

  int off = 0;
  for (int i = 0; i < e; ++i) off += counts[i];
  const int row0 = off + tml * 128;
  const int col0 = tn * 128;
  const size_t wbase = (size_t)e * DOUT * DIN + (size_t)col0 * DIN;

  f32x4 acc[4][4] = {};

  auto stage = [&](int buf, int kt) {
#pragma unroll
    for (int s = 0; s < 2; ++s) {
      int i = s * 256 + tid;
      int r = i >> 2, c = i & 3;
      const float* sa = Xf + (size_t)(row0 + r) * DIN + kt * 32 + c * 8;
      const float* sb = Wf + wbase + (size_t)r * DIN + kt * 32 + c * 8;
      f32x4 a0 = *(const f32x4*)sa;
      f32x4 a1 = *(const f32x4*)(sa + 4);
      f32x4 b0 = *(const f32x4*)sb;
      f32x4 b1 = *(const f32x4*)(sb + 4);
      short8 va, vb;
#pragma unroll
      for (int j = 0; j < 4; ++j) {
        va[j] = (short)f2bf(a0[j]); va[j + 4] = (short)f2bf(a1[j]);
        vb[j] = (short)f2bf(b0[j]); vb[j + 4] = (short)f2bf(b1[j]);
      }
      *(short8*)&lds[buf][0][i * 8] = va;
      *(short8*)&lds[buf][1][i * 8] = vb;
    }
  };

  auto compute = [&](int buf) {
    const int kc = lane >> 4;
    const int rr = lane & 15;
    short8 a[4], b[4];
    const u16* lA = lds[buf][0];
    const u16* lB = lds[buf][1];
#pragma unroll
    for (int m = 0; m < 4; ++m)
      a[m] = *(const short8*)(lA + (wr * 64 + m * 16 + rr) * 32 + kc * 8);
#pragma unroll
    for (int n = 0; n < 4; ++n)
      b[n] = *(const short8*)(lB + (wc * 64 + n * 16 + rr) * 32 + kc * 8);
#pragma unroll
    for (int m = 0; m < 4; ++m)
#pragma unroll
      for (int n = 0; n < 4; ++n)
        acc[m][n] = __builtin_amdgcn_mfma_f32_16x16x32_bf16(a[m], b[n], acc[m][n], 0, 0, 0);
  };

  stage(0, 0);
  for (int kt = 0; kt < DIN / 32; ++kt) {
    __syncthreads();
    if (kt + 1 < DIN / 32) stage((kt + 1) & 1, kt + 1);
    compute(kt & 1);
  }

  const int rbase = row0 + wr * 64;
  const int cbase = col0 + wc * 64;
#pragma unroll
  for (int n = 0; n < 4; ++n) {
    const int col = cbase + n * 16 + (lane & 15);
    const float bv = bias[e * DOUT + col];
#pragma unroll
    for (int m = 0; m < 4; ++m) {
      const int r0 = rbase + m * 16 + (lane >> 4) * 4;
#pragma unroll
      for (int j = 0; j < 4; ++j)
        C[(size_t)(r0 + j) * DOUT + col] = acc[m][n][j] + bv;
    }
  }
}

extern "C" void kernel_launch(void* const* d_in, const int* in_sizes, int n_in,
                              void* d_out, int out_size, void* d_ws, size_t ws_size,
                              hipStream_t stream) {
  const float* inp = (const float*)d_in[0];
  const int* counts = (const int*)d_in[1];
  const float* weight = (const float*)d_in[2];
  const float* bias = (const float*)d_in[3];
  float* out = (float*)d_out;

  const size_t nx = (size_t)NTOK * DIN;
  const size_t nw = (size_t)NE * DOUT * DIN;
  const size_t need = (nx + nw) * sizeof(u16);

  if (ws_size >= need) {
    u16* xb = (u16*)d_ws;
    u16* wb = xb + nx;
    cvt_f32_bf16<<<2048, 256, 0, stream>>>(inp, xb, nx);
    cvt_f32_bf16<<<2048, 256, 0, stream>>>(weight, wb, nw);
    const int grid = (NTOK / 256) * (DOUT / 256);  // 2048
    moe_gemm8<<<grid, 512, 131072, stream>>>(xb, wb, counts, bias, out);
  } else {
    const int grid = (NTOK / 128) * (DOUT / 128);  // 8192
    moe_gemm_fused<<<grid, 256, 0, stream>>>(inp, weight, counts, bias, out);
  }
}

// Round 7
// 810.007 us; speedup vs baseline: 1.9694x; 1.9694x over previous
//
#include <hip/hip_runtime.h>
#include <stdint.h>

typedef unsigned short u16;
typedef __attribute__((ext_vector_type(8))) short short8;
typedef __attribute__((ext_vector_type(4))) float f32x4;

#define NE   8
#define DIN  2048
#define DOUT 8192
#define NTOK 16384

__device__ __forceinline__ u16 f2bf(float f) {
  uint32_t u = __builtin_bit_cast(uint32_t, f);
  u += 0x7FFFu + ((u >> 16) & 1u);   // RNE (inputs are finite normals)
  return (u16)(u >> 16);
}

__global__ __launch_bounds__(256) void cvt_f32_bf16(const float* __restrict__ src,
                                                    u16* __restrict__ dst, size_t n) {
  size_t i = ((size_t)blockIdx.x * 256 + threadIdx.x) * 8;
  const size_t stride = (size_t)gridDim.x * 256 * 8;
  for (; i < n; i += stride) {
    f32x4 a = *(const f32x4*)(src + i);
    f32x4 b = *(const f32x4*)(src + i + 4);
    short8 o;
    o[0] = (short)f2bf(a[0]); o[1] = (short)f2bf(a[1]);
    o[2] = (short)f2bf(a[2]); o[3] = (short)f2bf(a[3]);
    o[4] = (short)f2bf(b[0]); o[5] = (short)f2bf(b[1]);
    o[6] = (short)f2bf(b[2]); o[7] = (short)f2bf(b[3]);
    *(short8*)(dst + i) = o;
  }
}

#define GLOAD_LDS16(g, l) __builtin_amdgcn_global_load_lds( \
    (const __attribute__((address_space(1))) void*)(g),     \
    (__attribute__((address_space(3))) void*)(l), 16, 0, 0)

// ---------------------------------------------------------------------------
// r7 = r3's proven skeleton (best: 625 us, 0 conflicts) with BALANCED
// quadrant phases (template's "4 or 8 ds_read_b128 per phase"):
//   ph1: rd a03(kh0)[4] + b(kh0)[4]; stage A0(t+1)         | bar MM(m0-3) bar
//   ph2: rd a47(kh0)[4];             stage B0(t+1); VMW(4) | bar MM(m4-7) bar
//   ph3: rd a03(kh1)[4] + b(kh1)[4]; stage A1(t+1)         | bar MM(m0-3) bar
//   ph4: rd a47(kh1)[4];             stage B1(t+1); VMW(4) | bar MM(m4-7) bar
// Each MM = 16 MFMA (4m x 4n quadrant). b[4] lives 2 phases; a[4] is
// phase-local => LOWER register pressure than r3 (r6's spill lesson).
// vmcnt (steady 8 in flight): VMW(4)@ph2 publishes cur-kh1 (first read ph3);
// VMW(4)@ph4 publishes next-kh0. Last tile: VMW(0)@ph2 (r2 lesson: counted
// wait with nothing new staged is a no-op race); ph4 wait skipped.
// Swizzle/staging/XCD mapping identical to r3 (measured 0 conflicts).
// ---------------------------------------------------------------------------
__global__ __launch_bounds__(512, 2) void moe_gemm8(
    const u16* __restrict__ Xb, const u16* __restrict__ Wb,
    const int* __restrict__ counts, const float* __restrict__ bias,
    float* __restrict__ C) {
  extern __shared__ u16 sm[];  // 65536 u16

  const int tid = threadIdx.x;
  const int l = tid & 63;
  const int wid = tid >> 6;      // 0..7
  const int wr = wid >> 2;       // 0..1  (M halves of 128)
  const int wc = wid & 3;        // 0..3  (N quarters of 64)

  // XCD-bijective swizzle: 2048 blocks, 256/XCD == tiles/expert => expert==XCD
  const int id = blockIdx.x;
  const int swz = (id & 7) * 256 + (id >> 3);
  const int e = swz >> 8;
  const int rem = swz & 255;
  const int tn = rem >> 3;       // 0..31 (8 consecutive blocks share B-panel)
  const int tm = rem & 7;        // 0..7

  int off = 0;
  for (int i = 0; i < e; ++i) off += counts[i];
  const int row0 = off + tm * 256;
  const int col0 = tn * 256;
  const size_t wbase = (size_t)e * DOUT * DIN + (size_t)col0 * DIN;

  // -- staging per-lane constants (pre-swizzled global source, linear dest)
  const int rl = l >> 2;                     // row within 16-row slice
  const int q = (l & 3) ^ ((l >> 3) & 3);    // source k-granule (inverse swz)
  const int s0 = wid * 2, s1 = s0 + 1;       // this wave's 2 slices of 16
  const u16* pA0 = Xb + (size_t)(row0 + s0 * 16 + rl) * DIN + q * 8;
  const u16* pA1 = Xb + (size_t)(row0 + s1 * 16 + rl) * DIN + q * 8;
  const u16* pB0 = Wb + wbase + (size_t)(s0 * 16 + rl) * DIN + q * 8;
  const u16* pB1 = Wb + wbase + (size_t)(s1 * 16 + rl) * DIN + q * 8;

  // -- fragment-read per-lane constants (16x16 layout, r3-verified swizzle)
  const int f0 = ((l & 15) >> 1) & 3;
  const int gph = (l >> 4) ^ f0;             // physical granule 0..3
  const int aoff = (wr * 128 + (l & 15)) * 32 + gph * 8;
  const int boff = (wc * 64 + (l & 15)) * 32 + gph * 8;

  f32x4 acc[8][4] = {};
  short8 a[4], b[4];

#define SMA(buf, kh) (sm + (buf) * 32768 + (kh) * 8192)
#define SMB(buf, kh) (sm + (buf) * 32768 + 16384 + (kh) * 8192)
#define STAGE_A(buf, kt, kh) do { const int ko = (kt) * 64 + (kh) * 32; \
    GLOAD_LDS16(pA0 + ko, SMA(buf, kh) + s0 * 512);                     \
    GLOAD_LDS16(pA1 + ko, SMA(buf, kh) + s1 * 512); } while (0)
#define STAGE_B(buf, kt, kh) do { const int ko = (kt) * 64 + (kh) * 32; \
    GLOAD_LDS16(pB0 + ko, SMB(buf, kh) + s0 * 512);                     \
    GLOAD_LDS16(pB1 + ko, SMB(buf, kh) + s1 * 512); } while (0)
#define RA4(buf, kh, mb) do { _Pragma("unroll") for (int mf = 0; mf < 4; ++mf) \
    a[mf] = *(const short8*)(SMA(buf, kh) + aoff + ((mb) + mf) * 512); } while (0)
#define RB4(buf, kh) do { _Pragma("unroll") for (int nf = 0; nf < 4; ++nf) \
    b[nf] = *(const short8*)(SMB(buf, kh) + boff + nf * 512); } while (0)
#define FENCE() asm volatile("" ::: "memory")
#define BAR() do { FENCE(); __builtin_amdgcn_s_barrier(); FENCE(); } while (0)
#define VMW(N) asm volatile("s_waitcnt vmcnt(" #N ")" ::: "memory")
#define MMQ(mb) do { __builtin_amdgcn_s_setprio(1);                                \
    _Pragma("unroll") for (int mf = 0; mf < 4; ++mf)                               \
      _Pragma("unroll") for (int nf = 0; nf < 4; ++nf)                             \
        acc[(mb) + mf][nf] =                                                       \
          __builtin_amdgcn_mfma_f32_16x16x32_bf16(a[mf], b[nf], acc[(mb) + mf][nf], 0, 0, 0); \
    __builtin_amdgcn_s_setprio(0); } while (0)

  const int NKT = DIN / 64;  // 32 K-tiles

  // prologue: tile 0 staged (kh0 first); VMW(4) publishes kh0, kh1 in flight.
  STAGE_A(0, 0, 0); STAGE_B(0, 0, 0); STAGE_A(0, 0, 1); STAGE_B(0, 0, 1);
  VMW(4);
  BAR();

  for (int kt = 0; kt < NKT; kt += 2) {
#define TILE(cur, nxt, t) do {                                          \
    const bool hn = (t) + 1 < NKT;                                      \
    /* ph1: kh0 quadrant m0-3 (8 reads) */                              \
    RA4(cur, 0, 0); RB4(cur, 0);                                        \
    if (hn) STAGE_A(nxt, (t) + 1, 0);                                   \
    BAR(); MMQ(0); BAR();                                               \
    /* ph2: kh0 quadrant m4-7 (4 reads) */                              \
    RA4(cur, 0, 4);                                                     \
    if (hn) { STAGE_B(nxt, (t) + 1, 0); VMW(4); } else VMW(0);          \
    BAR(); MMQ(4); BAR();                                               \
    /* ph3: kh1 quadrant m0-3 (8 reads) */                              \
    RA4(cur, 1, 0); RB4(cur, 1);                                        \
    if (hn) STAGE_A(nxt, (t) + 1, 1);                                   \
    BAR(); MMQ(0); BAR();                                               \
    /* ph4: kh1 quadrant m4-7 (4 reads) */                              \
    RA4(cur, 1, 4);                                                     \
    if (hn) { STAGE_B(nxt, (t) + 1, 1); VMW(4); }                       \
    BAR(); MMQ(4); BAR(); } while (0)
    TILE(0, 1, kt);
    TILE(1, 0, kt + 1);
#undef TILE
  }

  // epilogue: C/D layout col=lane&15, row=(lane>>4)*4+j  [m89]
  const int rb = row0 + wr * 128 + ((l >> 4) << 2);
  const int cb = col0 + wc * 64 + (l & 15);
#pragma unroll
  for (int n = 0; n < 4; ++n) {
    const int col = cb + n * 16;
    const float bv = bias[e * DOUT + col];
#pragma unroll
    for (int m = 0; m < 8; ++m) {
      const int r = rb + m * 16;
#pragma unroll
      for (int j = 0; j < 4; ++j)
        C[(size_t)(r + j) * DOUT + col] = acc[m][n][j] + bv;
    }
  }
}

// ---------------------------------------------------------------------------
// Fallback (ws too small): fused fp32->bf16 staging, 128x128 m97 structure.
// ---------------------------------------------------------------------------
__global__ __launch_bounds__(256) void moe_gemm_fused(
    const float* __restrict__ Xf, const float* __restrict__ Wf,
    const int* __restrict__ counts, const float* __restrict__ bias,
    float* __restrict__ C) {
  __shared__ __align__(16) u16 lds[2][2][128 * 32];

  const int tid = threadIdx.x;
  const int lane = tid & 63;
  const int wid = tid >> 6;
  const int wr = wid >> 1;
  const int wc = wid & 1;

  const int id = blockIdx.x;
  const int swz = (id & 7) * ((int)gridDim.x >> 3) + (id >> 3);
  const int e = swz >> 10;
  const int rem = swz & 1023;
  const int tn = rem >> 4;
  const int tml = rem & 15;

  int off = 0;
  for (int i = 0; i < e; ++i) off += counts[i];
  const int row0 = off + tml * 128;
  const int col0 = tn * 128;
  const size_t wbase = (size_t)e * DOUT * DIN + (size_t)col0 * DIN;

  f32x4 acc[4][4] = {};

  auto stage = [&](int buf, int kt) {
#pragma unroll
    for (int s = 0; s < 2; ++s) {
      int i = s * 256 + tid;
      int r = i >> 2, c = i & 3;
      const float* sa = Xf + (size_t)(row0 + r) * DIN + kt * 32 + c * 8;
      const float* sb = Wf + wbase + (size_t)r * DIN + kt * 32 + c * 8;
      f32x4 a0 = *(const f32x4*)sa;
      f32x4 a1 = *(const f32x4*)(sa + 4);
      f32x4 b0 = *(const f32x4*)sb;
      f32x4 b1 = *(const f32x4*)(sb + 4);
      short8 va, vb;
#pragma unroll
      for (int j = 0; j < 4; ++j) {
        va[j] = (short)f2bf(a0[j]); va[j + 4] = (short)f2bf(a1[j]);
        vb[j] = (short)f2bf(b0[j]); vb[j + 4] = (short)f2bf(b1[j]);
      }
      *(short8*)&lds[buf][0][i * 8] = va;
      *(short8*)&lds[buf][1][i * 8] = vb;
    }
  };

  auto compute = [&](int buf) {
    const int kc = lane >> 4;
    const int rr = lane & 15;
    short8 a[4], b[4];
    const u16* lA = lds[buf][0];
    const u16* lB = lds[buf][1];
#pragma unroll
    for (int m = 0; m < 4; ++m)
      a[m] = *(const short8*)(lA + (wr * 64 + m * 16 + rr) * 32 + kc * 8);
#pragma unroll
    for (int n = 0; n < 4; ++n)
      b[n] = *(const short8*)(lB + (wc * 64 + n * 16 + rr) * 32 + kc * 8);
#pragma unroll
    for (int m = 0; m < 4; ++m)
#pragma unroll
      for (int n = 0; n < 4; ++n)
        acc[m][n] = __builtin_amdgcn_mfma_f32_16x16x32_bf16(a[m], b[n], acc[m][n], 0, 0, 0);
  };

  stage(0, 0);
  for (int kt = 0; kt < DIN / 32; ++kt) {
    __syncthreads();
    if (kt + 1 < DIN / 32) stage((kt + 1) & 1, kt + 1);
    compute(kt & 1);
  }

  const int rbase = row0 + wr * 64;
  const int cbase = col0 + wc * 64;
#pragma unroll
  for (int n = 0; n < 4; ++n) {
    const int col = cbase + n * 16 + (lane & 15);
    const float bv = bias[e * DOUT + col];
#pragma unroll
    for (int m = 0; m < 4; ++m) {
      const int r0 = rbase + m * 16 + (lane >> 4) * 4;
#pragma unroll
      for (int j = 0; j < 4; ++j)
        C[(size_t)(r0 + j) * DOUT + col] = acc[m][n][j] + bv;
    }
  }
}

extern "C" void kernel_launch(void* const* d_in, const int* in_sizes, int n_in,
                              void* d_out, int out_size, void* d_ws, size_t ws_size,
                              hipStream_t stream) {
  const float* inp = (const float*)d_in[0];
  const int* counts = (const int*)d_in[1];
  const float* weight = (const float*)d_in[2];
  const float* bias = (const float*)d_in[3];
  float* out = (float*)d_out;

  const size_t nx = (size_t)NTOK * DIN;
  const size_t nw = (size_t)NE * DOUT * DIN;
  const size_t need = (nx + nw) * sizeof(u16);

  if (ws_size >= need) {
    u16* xb = (u16*)d_ws;
    u16* wb = xb + nx;
    cvt_f32_bf16<<<2048, 256, 0, stream>>>(inp, xb, nx);
    cvt_f32_bf16<<<2048, 256, 0, stream>>>(weight, wb, nw);
    const int grid = (NTOK / 256) * (DOUT / 256);  // 2048
    moe_gemm8<<<grid, 512, 131072, stream>>>(xb, wb, counts, bias, out);
  } else {
    const int grid = (NTOK / 128) * (DOUT / 128);  // 8192
    moe_gemm_fused<<<grid, 256, 0, stream>>>(inp, weight, counts, bias, out);
  }
}

// Round 8
// 792.249 us; speedup vs baseline: 2.0136x; 1.0224x over previous
//
#include <hip/hip_runtime.h>
#include <stdint.h>

typedef unsigned short u16;
typedef __attribute__((ext_vector_type(8))) short short8;
typedef __attribute__((ext_vector_type(4))) float f32x4;

#define NE   8
#define DIN  2048
#define DOUT 8192
#define NTOK 16384

__device__ __forceinline__ u16 f2bf(float f) {
  uint32_t u = __builtin_bit_cast(uint32_t, f);
  u += 0x7FFFu + ((u >> 16) & 1u);   // RNE (inputs are finite normals)
  return (u16)(u >> 16);
}

__global__ __launch_bounds__(256) void cvt_f32_bf16(const float* __restrict__ src,
                                                    u16* __restrict__ dst, size_t n) {
  size_t i = ((size_t)blockIdx.x * 256 + threadIdx.x) * 8;
  const size_t stride = (size_t)gridDim.x * 256 * 8;
  for (; i < n; i += stride) {
    f32x4 a = *(const f32x4*)(src + i);
    f32x4 b = *(const f32x4*)(src + i + 4);
    short8 o;
    o[0] = (short)f2bf(a[0]); o[1] = (short)f2bf(a[1]);
    o[2] = (short)f2bf(a[2]); o[3] = (short)f2bf(a[3]);
    o[4] = (short)f2bf(b[0]); o[5] = (short)f2bf(b[1]);
    o[6] = (short)f2bf(b[2]); o[7] = (short)f2bf(b[3]);
    *(short8*)(dst + i) = o;
  }
}

#define GLOAD_LDS16(g, l) __builtin_amdgcn_global_load_lds( \
    (const __attribute__((address_space(1))) void*)(g),     \
    (__attribute__((address_space(3))) void*)(l), 16, 0, 0)

// ---------------------------------------------------------------------------
// r8 = r7 with the POST-MFMA barriers removed (8 -> 4 barriers/K-tile).
// Phase = [reads (pre-barrier) ; stage ; (vmcnt) ; BAR(publish) ; MMQ].
// Barriers remain ONLY as publish points: VMW(4)+BAR@ph2 publishes cur-kh1
// (first read ph3); VMW(4)+BAR@ph4 publishes next-kh0 (first read t+1 ph1).
// Removing the trailing wall lets waves drift one phase apart, overlapping
// one wave's ds_reads with another's MFMA cluster (the lockstep alternation
// of {all-read}/{all-MFMA} windows was serializing the LDS and MFMA pipes).
// Region safety: stage writes target the opposite buffer; stage into
// (buf,khX) of tile t+2 is issued >=2 publish barriers after the last
// ds_read of that region. Reads never precede their publish barrier.
// Last tile: VMW(0)@ph2 (r2 lesson: counted wait with nothing staged races).
// Everything else identical to r7/r3 (geometry, swizzle w/ measured-0
// conflicts, staging order, setprio, XCD-expert mapping).
// ---------------------------------------------------------------------------
__global__ __launch_bounds__(512, 2) void moe_gemm8(
    const u16* __restrict__ Xb, const u16* __restrict__ Wb,
    const int* __restrict__ counts, const float* __restrict__ bias,
    float* __restrict__ C) {
  extern __shared__ u16 sm[];  // 65536 u16

  const int tid = threadIdx.x;
  const int l = tid & 63;
  const int wid = tid >> 6;      // 0..7
  const int wr = wid >> 2;       // 0..1  (M halves of 128)
  const int wc = wid & 3;        // 0..3  (N quarters of 64)

  // XCD-bijective swizzle: 2048 blocks, 256/XCD == tiles/expert => expert==XCD
  const int id = blockIdx.x;
  const int swz = (id & 7) * 256 + (id >> 3);
  const int e = swz >> 8;
  const int rem = swz & 255;
  const int tn = rem >> 3;       // 0..31 (8 consecutive blocks share B-panel)
  const int tm = rem & 7;        // 0..7

  int off = 0;
  for (int i = 0; i < e; ++i) off += counts[i];
  const int row0 = off + tm * 256;
  const int col0 = tn * 256;
  const size_t wbase = (size_t)e * DOUT * DIN + (size_t)col0 * DIN;

  // -- staging per-lane constants (pre-swizzled global source, linear dest)
  const int rl = l >> 2;                     // row within 16-row slice
  const int q = (l & 3) ^ ((l >> 3) & 3);    // source k-granule (inverse swz)
  const int s0 = wid * 2, s1 = s0 + 1;       // this wave's 2 slices of 16
  const u16* pA0 = Xb + (size_t)(row0 + s0 * 16 + rl) * DIN + q * 8;
  const u16* pA1 = Xb + (size_t)(row0 + s1 * 16 + rl) * DIN + q * 8;
  const u16* pB0 = Wb + wbase + (size_t)(s0 * 16 + rl) * DIN + q * 8;
  const u16* pB1 = Wb + wbase + (size_t)(s1 * 16 + rl) * DIN + q * 8;

  // -- fragment-read per-lane constants (16x16 layout, r3-verified swizzle)
  const int f0 = ((l & 15) >> 1) & 3;
  const int gph = (l >> 4) ^ f0;             // physical granule 0..3
  const int aoff = (wr * 128 + (l & 15)) * 32 + gph * 8;
  const int boff = (wc * 64 + (l & 15)) * 32 + gph * 8;

  f32x4 acc[8][4] = {};
  short8 a[4], b[4];

#define SMA(buf, kh) (sm + (buf) * 32768 + (kh) * 8192)
#define SMB(buf, kh) (sm + (buf) * 32768 + 16384 + (kh) * 8192)
#define STAGE_A(buf, kt, kh) do { const int ko = (kt) * 64 + (kh) * 32; \
    GLOAD_LDS16(pA0 + ko, SMA(buf, kh) + s0 * 512);                     \
    GLOAD_LDS16(pA1 + ko, SMA(buf, kh) + s1 * 512); } while (0)
#define STAGE_B(buf, kt, kh) do { const int ko = (kt) * 64 + (kh) * 32; \
    GLOAD_LDS16(pB0 + ko, SMB(buf, kh) + s0 * 512);                     \
    GLOAD_LDS16(pB1 + ko, SMB(buf, kh) + s1 * 512); } while (0)
#define RA4(buf, kh, mb) do { _Pragma("unroll") for (int mf = 0; mf < 4; ++mf) \
    a[mf] = *(const short8*)(SMA(buf, kh) + aoff + ((mb) + mf) * 512); } while (0)
#define RB4(buf, kh) do { _Pragma("unroll") for (int nf = 0; nf < 4; ++nf) \
    b[nf] = *(const short8*)(SMB(buf, kh) + boff + nf * 512); } while (0)
#define FENCE() asm volatile("" ::: "memory")
#define BAR() do { FENCE(); __builtin_amdgcn_s_barrier(); FENCE(); } while (0)
#define VMW(N) asm volatile("s_waitcnt vmcnt(" #N ")" ::: "memory")
#define MMQ(mb) do { __builtin_amdgcn_s_setprio(1);                                \
    _Pragma("unroll") for (int mf = 0; mf < 4; ++mf)                               \
      _Pragma("unroll") for (int nf = 0; nf < 4; ++nf)                             \
        acc[(mb) + mf][nf] =                                                       \
          __builtin_amdgcn_mfma_f32_16x16x32_bf16(a[mf], b[nf], acc[(mb) + mf][nf], 0, 0, 0); \
    __builtin_amdgcn_s_setprio(0); } while (0)

  const int NKT = DIN / 64;  // 32 K-tiles

  // prologue: tile 0 staged (kh0 first); VMW(4) publishes kh0, kh1 in flight.
  STAGE_A(0, 0, 0); STAGE_B(0, 0, 0); STAGE_A(0, 0, 1); STAGE_B(0, 0, 1);
  VMW(4);
  BAR();

  for (int kt = 0; kt < NKT; kt += 2) {
#define TILE(cur, nxt, t) do {                                          \
    const bool hn = (t) + 1 < NKT;                                      \
    /* ph1: kh0 m0-3 (8 reads pre-bar) */                               \
    RA4(cur, 0, 0); RB4(cur, 0);                                        \
    if (hn) STAGE_A(nxt, (t) + 1, 0);                                   \
    BAR(); MMQ(0);                                                      \
    /* ph2: kh0 m4-7 (4 reads) ; publish cur-kh1 */                     \
    RA4(cur, 0, 4);                                                     \
    if (hn) { STAGE_B(nxt, (t) + 1, 0); VMW(4); } else VMW(0);          \
    BAR(); MMQ(4);                                                      \
    /* ph3: kh1 m0-3 (8 reads) */                                       \
    RA4(cur, 1, 0); RB4(cur, 1);                                        \
    if (hn) STAGE_A(nxt, (t) + 1, 1);                                   \
    BAR(); MMQ(0);                                                      \
    /* ph4: kh1 m4-7 (4 reads) ; publish next-kh0 */                    \
    RA4(cur, 1, 4);                                                     \
    if (hn) { STAGE_B(nxt, (t) + 1, 1); VMW(4); }                       \
    BAR(); MMQ(4); } while (0)
    TILE(0, 1, kt);
    TILE(1, 0, kt + 1);
#undef TILE
  }

  // epilogue: C/D layout col=lane&15, row=(lane>>4)*4+j  [m89]
  const int rb = row0 + wr * 128 + ((l >> 4) << 2);
  const int cb = col0 + wc * 64 + (l & 15);
#pragma unroll
  for (int n = 0; n < 4; ++n) {
    const int col = cb + n * 16;
    const float bv = bias[e * DOUT + col];
#pragma unroll
    for (int m = 0; m < 8; ++m) {
      const int r = rb + m * 16;
#pragma unroll
      for (int j = 0; j < 4; ++j)
        C[(size_t)(r + j) * DOUT + col] = acc[m][n][j] + bv;
    }
  }
}

// ---------------------------------------------------------------------------
// Fallback (ws too small): fused fp32->bf16 staging, 128x128 m97 structure.
// ---------------------------------------------------------------------------
__global__ __launch_bounds__(256) void moe_gemm_fused(
    const float* __restrict__ Xf, const float* __restrict__ Wf,
    const int* __restrict__ counts, const float* __restrict__ bias,
    float* __restrict__ C) {
  __shared__ __align__(16) u16 lds[2][2][128 * 32];

  const int tid = threadIdx.x;
  const int lane = tid & 63;
  const int wid = tid >> 6;
  const int wr = wid >> 1;
  const int wc = wid & 1;

  const int id = blockIdx.x;
  const int swz = (id & 7) * ((int)gridDim.x >> 3) + (id >> 3);
  const int e = swz >> 10;
  const int rem = swz & 1023;
  const int tn = rem >> 4;
  const int tml = rem & 15;

  int off = 0;
  for (int i = 0; i < e; ++i) off += counts[i];
  const int row0 = off + tml * 128;
  const int col0 = tn * 128;
  const size_t wbase = (size_t)e * DOUT * DIN + (size_t)col0 * DIN;

  f32x4 acc[4][4] = {};

  auto stage = [&](int buf, int kt) {
#pragma unroll
    for (int s = 0; s < 2; ++s) {
      int i = s * 256 + tid;
      int r = i >> 2, c = i & 3;
      const float* sa = Xf + (size_t)(row0 + r) * DIN + kt * 32 + c * 8;
      const float* sb = Wf + wbase + (size_t)r * DIN + kt * 32 + c * 8;
      f32x4 a0 = *(const f32x4*)sa;
      f32x4 a1 = *(const f32x4*)(sa + 4);
      f32x4 b0 = *(const f32x4*)sb;
      f32x4 b1 = *(const f32x4*)(sb + 4);
      short8 va, vb;
#pragma unroll
      for (int j = 0; j < 4; ++j) {
        va[j] = (short)f2bf(a0[j]); va[j + 4] = (short)f2bf(a1[j]);
        vb[j] = (short)f2bf(b0[j]); vb[j + 4] = (short)f2bf(b1[j]);
      }
      *(short8*)&lds[buf][0][i * 8] = va;
      *(short8*)&lds[buf][1][i * 8] = vb;
    }
  };

  auto compute = [&](int buf) {
    const int kc = lane >> 4;
    const int rr = lane & 15;
    short8 a[4], b[4];
    const u16* lA = lds[buf][0];
    const u16* lB = lds[buf][1];
#pragma unroll
    for (int m = 0; m < 4; ++m)
      a[m] = *(const short8*)(lA + (wr * 64 + m * 16 + rr) * 32 + kc * 8);
#pragma unroll
    for (int n = 0; n < 4; ++n)
      b[n] = *(const short8*)(lB + (wc * 64 + n * 16 + rr) * 32 + kc * 8);
#pragma unroll
    for (int m = 0; m < 4; ++m)
#pragma unroll
      for (int n = 0; n < 4; ++n)
        acc[m][n] = __builtin_amdgcn_mfma_f32_16x16x32_bf16(a[m], b[n], acc[m][n], 0, 0, 0);
  };

  stage(0, 0);
  for (int kt = 0; kt < DIN / 32; ++kt) {
    __syncthreads();
    if (kt + 1 < DIN / 32) stage((kt + 1) & 1, kt + 1);
    compute(kt & 1);
  }

  const int rbase = row0 + wr * 64;
  const int cbase = col0 + wc * 64;
#pragma unroll
  for (int n = 0; n < 4; ++n) {
    const int col = cbase + n * 16 + (lane & 15);
    const float bv = bias[e * DOUT + col];
#pragma unroll
    for (int m = 0; m < 4; ++m) {
      const int r0 = rbase + m * 16 + (lane >> 4) * 4;
#pragma unroll
      for (int j = 0; j < 4; ++j)
        C[(size_t)(r0 + j) * DOUT + col] = acc[m][n][j] + bv;
    }
  }
}

extern "C" void kernel_launch(void* const* d_in, const int* in_sizes, int n_in,
                              void* d_out, int out_size, void* d_ws, size_t ws_size,
                              hipStream_t stream) {
  const float* inp = (const float*)d_in[0];
  const int* counts = (const int*)d_in[1];
  const float* weight = (const float*)d_in[2];
  const float* bias = (const float*)d_in[3];
  float* out = (float*)d_out;

  const size_t nx = (size_t)NTOK * DIN;
  const size_t nw = (size_t)NE * DOUT * DIN;
  const size_t need = (nx + nw) * sizeof(u16);

  if (ws_size >= need) {
    u16* xb = (u16*)d_ws;
    u16* wb = xb + nx;
    cvt_f32_bf16<<<2048, 256, 0, stream>>>(inp, xb, nx);
    cvt_f32_bf16<<<2048, 256, 0, stream>>>(weight, wb, nw);
    const int grid = (NTOK / 256) * (DOUT / 256);  // 2048
    moe_gemm8<<<grid, 512, 131072, stream>>>(xb, wb, counts, bias, out);
  } else {
    const int grid = (NTOK / 128) * (DOUT / 128);  // 8192
    moe_gemm_fused<<<grid, 256, 0, stream>>>(inp, weight, counts, bias, out);
  }
}